// Round 7
// baseline (691.804 us; speedup 1.0000x reference)
//
#include <hip/hip_runtime.h>

typedef unsigned short u16;
typedef unsigned int u32;
typedef __bf16 bf16x8 __attribute__((ext_vector_type(8)));
typedef float f32x4 __attribute__((ext_vector_type(4)));

constexpr int Bn = 8, Tn = 2048, En = 1024, Hn = 64;
constexpr int Mrows = Bn * Tn;  // 16384
// softmax in exp2 domain: fold E^-0.5 * log2(e) into q pre-scale
constexpr float SCALE_LOG2E = 0.03125f * 1.4426950408889634f;

// ---- dtype sniff: packed bf16 vs fp32 (bf16 exponent bits land in [96,144]) ----
__device__ __forceinline__ bool sniff_bf16(const u32* xw) {
  int cnt = 0;
#pragma unroll 1
  for (int i = 0; i < 64; ++i) {
    u32 e = (xw[i] >> 7) & 0xFFu;
    cnt += (e >= 96u && e <= 144u) ? 1 : 0;
  }
  return cnt >= 48;
}

__device__ __forceinline__ u16 f2bf(float f) {  // RNE f32 -> bf16
  u32 u = __float_as_uint(f);
  return (u16)((u + 0x7fffu + ((u >> 16) & 1u)) >> 16);
}

// ---------- phase 0: W [E][H] -> Wt [3][H][E] bf16 (contiguous-k A-frags) ----------
// R7: reverted to [E][H] reference layout (einsum 'eh'). R2-R5's math was correct;
// the failure was the OUTPUT dtype (bf16 written into an fp32 buffer).
__global__ void wt_kernel(const void* __restrict__ xv, const void* __restrict__ Wkv,
                          const void* __restrict__ Wqv, const void* __restrict__ Wvv,
                          u16* __restrict__ Wt) {
  const bool isbf = sniff_bf16((const u32*)xv);
  int tid = blockIdx.x * 256 + threadIdx.x;  // 3*64*1024 = 196608 exact
  int mat = tid >> 16;
  int rem = tid & 65535;
  int h = rem >> 10, k = rem & 1023;
  const void* W = (mat == 0) ? Wkv : (mat == 1) ? Wqv : Wvv;
  u16 val;
  if (isbf) val = ((const u16*)W)[k * 64 + h];
  else      val = f2bf(((const float*)W)[k * 64 + h]);
  Wt[tid] = val;
}

// ---------- phase 1: QKV projection via mfma_f32_16x16x32_bf16 ----------
// D[m=h][n=row] = Wt(h,k) * x^T(k,row). Wave: 16 rows x 12 m-tiles (3 mats x 4 h).
// (Implementation cross-validated: R2-MFMA == R3-scalar-VALU bit-identical.)
__global__ __launch_bounds__(256, 1) void qkv_kernel(
    const void* __restrict__ xv, const u16* __restrict__ Wt,
    float* __restrict__ K, float* __restrict__ Q, float* __restrict__ V) {
  const bool isbf = sniff_bf16((const u32*)xv);
  const int w = threadIdx.x >> 6, lane = threadIdx.x & 63;
  const int quad = lane >> 4, l16 = lane & 15;
  const int r0 = blockIdx.x * 64 + w * 16;
  const u16* wp = Wt + (size_t)l16 * En + quad * 8;
  f32x4 acc[12];
  f32x4 zero = {0.f, 0.f, 0.f, 0.f};
#pragma unroll
  for (int i = 0; i < 12; ++i) acc[i] = zero;

  if (isbf) {
    const u16* xp = (const u16*)xv + (size_t)(r0 + l16) * En + quad * 8;
    for (int k0 = 0; k0 < En; k0 += 32) {
      bf16x8 bfr = *(const bf16x8*)(xp + k0);
#pragma unroll
      for (int mt = 0; mt < 12; ++mt) {
        bf16x8 afr = *(const bf16x8*)(wp + (size_t)(mt * 16) * En + k0);
        acc[mt] = __builtin_amdgcn_mfma_f32_16x16x32_bf16(afr, bfr, acc[mt], 0, 0, 0);
      }
    }
  } else {
    const float* xp = (const float*)xv + (size_t)(r0 + l16) * En + quad * 8;
    for (int k0 = 0; k0 < En; k0 += 32) {
      float4 f0 = *(const float4*)(xp + k0);
      float4 f1 = *(const float4*)(xp + k0 + 4);
      bf16x8 bfr;
      bfr[0] = (__bf16)f0.x; bfr[1] = (__bf16)f0.y;
      bfr[2] = (__bf16)f0.z; bfr[3] = (__bf16)f0.w;
      bfr[4] = (__bf16)f1.x; bfr[5] = (__bf16)f1.y;
      bfr[6] = (__bf16)f1.z; bfr[7] = (__bf16)f1.w;
#pragma unroll
      for (int mt = 0; mt < 12; ++mt) {
        bf16x8 afr = *(const bf16x8*)(wp + (size_t)(mt * 16) * En + k0);
        acc[mt] = __builtin_amdgcn_mfma_f32_16x16x32_bf16(afr, bfr, acc[mt], 0, 0, 0);
      }
    }
  }

  float* outs[3] = {K, Q, V};
  const int row = r0 + l16;
#pragma unroll
  for (int mt = 0; mt < 12; ++mt) {
    float* dst = outs[mt >> 2] + (size_t)row * Hn + (mt & 3) * 16 + quad * 4;
    *(f32x4*)dst = acc[mt];
  }
}

// ---------- phase 2: causal flash attention, VALU, lane=query, fp32 Q/K/V ----------
// (Cross-validated vs R5's sequential textbook attention: identical output.)
// R7 FIX: output is FP32 (reference returns float32; template: "else float*").
__global__ __launch_bounds__(512, 1) void attn_kernel(
    const float* __restrict__ Q, const float* __restrict__ K,
    const float* __restrict__ V, float* __restrict__ out) {
  const int w = threadIdx.x >> 6, lane = threadIdx.x & 63;
  const int b = blockIdx.x >> 5, qt = blockIdx.x & 31;
  const int q_abs = qt * 64 + lane;
  const float* Kb = K + (size_t)b * Tn * Hn;
  const float* Vb = V + (size_t)b * Tn * Hn;
  const int limit = qt * 64 + 64;      // keys needed by this tile
  const int chunk = limit >> 3;        // limit is a multiple of 64
  const int lo = w * chunk;
  const int hi_l = min(lo + chunk, q_abs + 1);  // per-lane causal prefix

  float q[64], o[64];
  {
    const float4* qp = (const float4*)(Q + ((size_t)b * Tn + q_abs) * Hn);
#pragma unroll
    for (int i = 0; i < 16; ++i) {
      float4 t = qp[i];
      q[4 * i + 0] = t.x * SCALE_LOG2E;
      q[4 * i + 1] = t.y * SCALE_LOG2E;
      q[4 * i + 2] = t.z * SCALE_LOG2E;
      q[4 * i + 3] = t.w * SCALE_LOG2E;
    }
  }
#pragma unroll
  for (int h = 0; h < 64; ++h) o[h] = 0.f;
  float m = -1e30f, l = 0.f;

  for (int j = lo; j < hi_l; ++j) {
    const float4* kr = (const float4*)(Kb + (size_t)j * Hn);
    float s0 = 0.f, s1 = 0.f, s2 = 0.f, s3 = 0.f;
#pragma unroll
    for (int i = 0; i < 16; ++i) {
      float4 kk = kr[i];
      s0 += q[4 * i + 0] * kk.x;
      s1 += q[4 * i + 1] * kk.y;
      s2 += q[4 * i + 2] * kk.z;
      s3 += q[4 * i + 3] * kk.w;
    }
    float s = (s0 + s1) + (s2 + s3);
    if (s > m) {  // lazy rescale only on a new running max
      float ar = __builtin_amdgcn_exp2f(m - s);
      m = s;
      l *= ar;
#pragma unroll
      for (int h = 0; h < 64; ++h) o[h] *= ar;
    }
    float p = __builtin_amdgcn_exp2f(s - m);
    l += p;
    const float4* vr = (const float4*)(Vb + (size_t)j * Hn);
#pragma unroll
    for (int i = 0; i < 16; ++i) {
      float4 vv = vr[i];
      o[4 * i + 0] += p * vv.x;
      o[4 * i + 1] += p * vv.y;
      o[4 * i + 2] += p * vv.z;
      o[4 * i + 3] += p * vv.w;
    }
  }

  // ---- cross-wave combine in LDS ----
  __shared__ float m_sh[8][64];
  __shared__ float l_sh[8][64];
  __shared__ float o_sh[64][65];  // +1 pad
  m_sh[w][lane] = m;
  l_sh[w][lane] = l;
  for (int i = threadIdx.x; i < 64 * 65; i += 512) (&o_sh[0][0])[i] = 0.f;
  __syncthreads();
  float mg = m_sh[0][lane];
#pragma unroll
  for (int ww = 1; ww < 8; ++ww) mg = fmaxf(mg, m_sh[ww][lane]);
  const float aw = (l > 0.f) ? __builtin_amdgcn_exp2f(m - mg) : 0.f;
  for (int r = 0; r < 8; ++r) {  // deterministic serialized accumulation
    if (w == r && aw > 0.f) {
#pragma unroll
      for (int h = 0; h < 64; ++h) o_sh[lane][h] += aw * o[h];
    }
    __syncthreads();
  }
  // epilogue: thread -> (query qq, 8-wide h chunk); fp32 stores (2x float4)
  const int qq = threadIdx.x >> 3, h0 = (threadIdx.x & 7) * 8;
  float mg2 = m_sh[0][qq];
#pragma unroll
  for (int ww = 1; ww < 8; ++ww) mg2 = fmaxf(mg2, m_sh[ww][qq]);
  float lg = 0.f;
#pragma unroll
  for (int ww = 0; ww < 8; ++ww) {
    float lw = l_sh[ww][qq];
    lg += (lw > 0.f) ? __builtin_amdgcn_exp2f(m_sh[ww][qq] - mg2) * lw : 0.f;
  }
  const float inv = 1.f / lg;
  float* op = out + ((size_t)b * Tn + qt * 64 + qq) * Hn + h0;
  float4 v0, v1;
  v0.x = o_sh[qq][h0 + 0] * inv;
  v0.y = o_sh[qq][h0 + 1] * inv;
  v0.z = o_sh[qq][h0 + 2] * inv;
  v0.w = o_sh[qq][h0 + 3] * inv;
  v1.x = o_sh[qq][h0 + 4] * inv;
  v1.y = o_sh[qq][h0 + 5] * inv;
  v1.z = o_sh[qq][h0 + 6] * inv;
  v1.w = o_sh[qq][h0 + 7] * inv;
  *(float4*)op = v0;
  *(float4*)(op + 4) = v1;
}

extern "C" void kernel_launch(void* const* d_in, const int* in_sizes, int n_in,
                              void* d_out, int out_size, void* d_ws, size_t ws_size,
                              hipStream_t stream) {
  // Order-agnostic input mapping (R4 proved it selects the documented order).
  const void* x = nullptr;
  const void* Ws[3] = {nullptr, nullptr, nullptr};
  int wj = 0;
  for (int i = 0; i < n_in; ++i) {
    if (in_sizes[i] == Bn * Tn * En) x = d_in[i];
    else if (wj < 3) Ws[wj++] = d_in[i];
  }
  const void* Wk = Ws[0];
  const void* Wq = Ws[1];
  const void* Wv = Ws[2];

  // ws: Q,K,V fp32 [16384][64] (4 MB each) + Wt bf16 (384 KB). Fits (R2==R3 proof).
  float* Qf = (float*)d_ws;
  float* Kf = Qf + (size_t)Mrows * Hn;
  float* Vf = Kf + (size_t)Mrows * Hn;
  u16* Wt = (u16*)(Vf + (size_t)Mrows * Hn);

  wt_kernel<<<768, 256, 0, stream>>>(x, Wk, Wq, Wv, Wt);
  qkv_kernel<<<Mrows / 64, 256, 0, stream>>>(x, Wt, Kf, Qf, Vf);
  attn_kernel<<<Bn * (Tn / 64), 512, 0, stream>>>(Qf, Kf, Vf, (float*)d_out);
}